// Round 6
// baseline (313.791 us; speedup 1.0000x reference)
//
#include <hip/hip_runtime.h>

#define NTOK  8192
#define NHEAD 16
#define DDIM  128
#define HDIM  384
#define NEXP  8
#define TILE  64
#define ENTRIES 2176   // per-slot work entries; worst case lid = 7 + 8*269 = 2159

typedef __attribute__((ext_vector_type(8))) short short8;   // 8 x bf16 (4 VGPRs)
typedef __attribute__((ext_vector_type(4))) float f32x4;    // MFMA accumulator

// ---------------- workspace layout (bytes) ----------------
#define SZ_W1P   (8UL*16*4*24*512*2)          // 12,582,912
#define OFF_W1P  0UL
#define OFF_WGP  (OFF_W1P + SZ_W1P)
#define OFF_W2P  (OFF_WGP + SZ_W1P)
#define SZ_W2P   (8UL*16*12*8*512*2)          // 12,582,912
#define OFF_ROUT (OFF_W2P + SZ_W2P)           // Routing[8192], 16B each
#define OFF_CNT  (OFF_ROUT + 8192UL*16)       // cnt[16], cur[16]
#define OFF_TAB  (OFF_CNT + 256)              // int4[2][ENTRIES]
#define OFF_LIST (OFF_TAB + 2UL*ENTRIES*16)   // int[2][8192]
#define OFF_WL   (OFF_LIST + 2UL*8192*4)      // float[2][8192]

struct Routing { int i0, i1; float w0, w1; };

__device__ __forceinline__ unsigned short f2bf(float f) {
  unsigned int u = __float_as_uint(f);
  u += 0x7fffu + ((u >> 16) & 1u);            // round-to-nearest-even
  return (unsigned short)(u >> 16);
}

// ---------------- weight conversion: fp32 -> bf16 fragment-packed ----------------
// w1/w_gate: [e][n][d=128][h=384] -> frag [en][kk(4)][ct(24)][lane(64)][8]
// element (kk,ct,lane,j) = src[d = kk*32 + (lane>>4)*8 + j][h = ct*16 + (lane&15)]
__global__ __launch_bounds__(256) void convA_kernel(
    const float* __restrict__ w1, const float* __restrict__ wg,
    unsigned short* __restrict__ w1P, unsigned short* __restrict__ wgP) {
  __shared__ float ls[32][388];
  const int kk = blockIdx.x;          // 0..3
  const int en = blockIdx.y;          // 0..127
  const float* src = (blockIdx.z == 0 ? w1 : wg) + ((size_t)en * DDIM + kk * 32) * HDIM;
  unsigned short* dst = (blockIdx.z == 0 ? w1P : wgP) + ((size_t)en * 4 + kk) * (24 * 512);
  const int tid = threadIdx.x;
  #pragma unroll
  for (int i = 0; i < 12; ++i) {
    int f4 = i * 256 + tid;           // 3072 float4 = 32x384
    int row = f4 / 96, c4 = f4 % 96;
    float4 v = reinterpret_cast<const float4*>(src + (size_t)row * HDIM)[c4];
    ls[row][c4*4+0] = v.x; ls[row][c4*4+1] = v.y;
    ls[row][c4*4+2] = v.z; ls[row][c4*4+3] = v.w;
  }
  __syncthreads();
  #pragma unroll
  for (int i = 0; i < 6; ++i) {
    int fid = i * 256 + tid;          // 1536 = 24ct * 64lane
    int ct = fid >> 6, lane = fid & 63;
    int r0 = (lane >> 4) * 8, c = ct * 16 + (lane & 15);
    unsigned short o[8];
    #pragma unroll
    for (int j = 0; j < 8; ++j) o[j] = f2bf(ls[r0 + j][c]);
    reinterpret_cast<uint4*>(dst + (size_t)(ct * 64 + lane) * 8)[0] =
        make_uint4((unsigned)o[0] | ((unsigned)o[1] << 16),
                   (unsigned)o[2] | ((unsigned)o[3] << 16),
                   (unsigned)o[4] | ((unsigned)o[5] << 16),
                   (unsigned)o[6] | ((unsigned)o[7] << 16));
  }
}

// w2: [e][n][h=384][d=128] -> frag [en][kk(12)][ct(8)][lane(64)][8]
// element = src[h = kk*32 + (lane>>4)*8 + j][d = ct*16 + (lane&15)]
__global__ __launch_bounds__(256) void convB_kernel(
    const float* __restrict__ w2, unsigned short* __restrict__ w2P) {
  __shared__ float ls[32][132];
  const int kk = blockIdx.x;          // 0..11
  const int en = blockIdx.y;
  const float* src = w2 + ((size_t)en * HDIM + kk * 32) * DDIM;
  unsigned short* dst = w2P + ((size_t)en * 12 + kk) * (8 * 512);
  const int tid = threadIdx.x;
  #pragma unroll
  for (int i = 0; i < 4; ++i) {
    int f4 = i * 256 + tid;           // 1024 float4 = 32x128
    int row = f4 >> 5, c4 = f4 & 31;
    float4 v = reinterpret_cast<const float4*>(src + (size_t)row * DDIM)[c4];
    ls[row][c4*4+0] = v.x; ls[row][c4*4+1] = v.y;
    ls[row][c4*4+2] = v.z; ls[row][c4*4+3] = v.w;
  }
  __syncthreads();
  #pragma unroll
  for (int i = 0; i < 2; ++i) {
    int fid = i * 256 + tid;          // 512 = 8ct * 64lane
    int ct = fid >> 6, lane = fid & 63;
    int r0 = (lane >> 4) * 8, c = ct * 16 + (lane & 15);
    unsigned short o[8];
    #pragma unroll
    for (int j = 0; j < 8; ++j) o[j] = f2bf(ls[r0 + j][c]);
    reinterpret_cast<uint4*>(dst + (size_t)(ct * 64 + lane) * 8)[0] =
        make_uint4((unsigned)o[0] | ((unsigned)o[1] << 16),
                   (unsigned)o[2] | ((unsigned)o[3] << 16),
                   (unsigned)o[4] | ((unsigned)o[5] << 16),
                   (unsigned)o[6] | ((unsigned)o[7] << 16));
  }
}

// ---------------- router: no LDS, no atomics, 1 wave = 4 tokens ----------------
__global__ __launch_bounds__(256) void router_kernel(
    const float* __restrict__ x, const float* __restrict__ rw,
    Routing* __restrict__ routing) {
  const int lane = threadIdx.x & 63;
  const int wgid = blockIdx.x * 4 + (threadIdx.x >> 6);
  const int tok0 = wgid * 4;
  float acc[4][8];
  #pragma unroll
  for (int t = 0; t < 4; ++t)
    #pragma unroll
    for (int e = 0; e < 8; ++e) acc[t][e] = 0.f;
  const float4* xr = reinterpret_cast<const float4*>(x);
  const float4* wr = reinterpret_cast<const float4*>(rw);
  #pragma unroll
  for (int c = 0; c < 8; ++c) {
    float4 wv[8];
    #pragma unroll
    for (int e = 0; e < 8; ++e) wv[e] = wr[e * 512 + c * 64 + lane];
    #pragma unroll
    for (int t = 0; t < 4; ++t) {
      float4 xv = xr[(size_t)(tok0 + t) * 512 + c * 64 + lane];
      #pragma unroll
      for (int e = 0; e < 8; ++e)
        acc[t][e] += xv.x * wv[e].x + xv.y * wv[e].y + xv.z * wv[e].z + xv.w * wv[e].w;
    }
  }
  // xor 1,2,4: each 8-lane group holds its partial sum for all 8 experts
  #pragma unroll
  for (int t = 0; t < 4; ++t)
    #pragma unroll
    for (int e = 0; e < 8; ++e) {
      acc[t][e] += __shfl_xor(acc[t][e], 1);
      acc[t][e] += __shfl_xor(acc[t][e], 2);
      acc[t][e] += __shfl_xor(acc[t][e], 4);
    }
  const int l3 = lane & 7;
  #pragma unroll
  for (int t = 0; t < 4; ++t) {
    // lane selects expert (lane&7)'s partial, then sums across the 8 groups
    float v0 = (l3 & 1) ? acc[t][1] : acc[t][0];
    float v1 = (l3 & 1) ? acc[t][3] : acc[t][2];
    float v2 = (l3 & 1) ? acc[t][5] : acc[t][4];
    float v3 = (l3 & 1) ? acc[t][7] : acc[t][6];
    float u0 = (l3 & 2) ? v1 : v0;
    float u1 = (l3 & 2) ? v3 : v2;
    float sel = (l3 & 4) ? u1 : u0;
    sel += __shfl_xor(sel, 8);
    sel += __shfl_xor(sel, 16);
    sel += __shfl_xor(sel, 32);
    // lane e (e<8) now holds logit L_e; broadcast all 8 to every lane
    float le[8];
    #pragma unroll
    for (int e = 0; e < 8; ++e) le[e] = __shfl(sel, e);
    if (lane == 0) {
      int tok = tok0 + t;
      int i0 = 0; float m0 = le[0];
      #pragma unroll
      for (int e = 1; e < 8; ++e) if (le[e] > m0) { m0 = le[e]; i0 = e; }
      int i1 = -1; float m1 = -3.4e38f;
      #pragma unroll
      for (int e = 0; e < 8; ++e) if (e != i0 && le[e] > m1) { m1 = le[e]; i1 = e; }
      float ed = __expf(m1 - m0);                 // <= 1
      Routing r; r.i0 = i0; r.i1 = i1;
      r.w0 = 1.f / (1.f + ed); r.w1 = ed / (1.f + ed);
      routing[tok] = r;
    }
  }
}

// ---------------- count: one block per (slot,expert), atomic-free ----------------
__global__ __launch_bounds__(256) void count_kernel(
    const Routing* __restrict__ routing, int* __restrict__ cnt) {
  const int s = blockIdx.x >> 3, e = blockIdx.x & 7;
  const int tid = threadIdx.x;
  int c = 0;
  for (int t = tid; t < NTOK; t += 256) {
    Routing r = routing[t];
    c += ((s == 0 ? r.i0 : r.i1) == e);
  }
  c += __shfl_xor(c, 32); c += __shfl_xor(c, 16); c += __shfl_xor(c, 8);
  c += __shfl_xor(c, 4);  c += __shfl_xor(c, 2);  c += __shfl_xor(c, 1);
  __shared__ int wsum[4];
  if ((tid & 63) == 0) wsum[tid >> 6] = c;
  __syncthreads();
  if (tid == 0) cnt[blockIdx.x] = wsum[0] + wsum[1] + wsum[2] + wsum[3];
}

// ---------------- build: prefix offsets + XCD-grouped work table ----------------
__global__ void build_kernel(const int* __restrict__ cnt, int* __restrict__ cur,
                             int4* __restrict__ table) {
  const int tid = threadIdx.x;
  for (int i = tid; i < 2 * ENTRIES; i += 256)
    table[i] = make_int4(0, 0, 0, 0);          // rcnt==0 sentinel -> early exit
  __syncthreads();
  if (tid < 16) {                               // cur[s*8+e] = per-slot prefix
    int s = tid >> 3, e = tid & 7;
    int base = 0;
    for (int k = 0; k < e; ++k) base += cnt[s * 8 + k];
    cur[tid] = base;
  }
  __syncthreads();
  if (tid < 16) {                               // one thread per (slot, xcd)
    int s = tid >> 3, xcd = tid & 7;
    int j = 0;
    int base = 0;
    for (int e = 0; e < 8; ++e) {
      int c = cnt[s * 8 + e];
      #pragma unroll
      for (int nn = 0; nn < 2; ++nn) {
        int n = xcd + nn * 8;                   // heads with n%8 == xcd
        for (int t = 0; t < c; t += TILE) {
          int rc = c - t; if (rc > TILE) rc = TILE;
          table[s * ENTRIES + xcd + 8 * j] = make_int4(e, base + t, rc, n);
          ++j;
        }
      }
      base += c;
    }
  }
}

// ---------------- compact: ordered, atomic-free scatter via block scan ----------------
__global__ __launch_bounds__(256) void compact_kernel(
    const Routing* __restrict__ routing, const int* __restrict__ cur,
    int* __restrict__ list, float* __restrict__ wl) {
  const int s = blockIdx.x >> 3, e = blockIdx.x & 7;
  const int tid = threadIdx.x;
  __shared__ int ps[256];
  int myc = 0;
  for (int t = tid; t < NTOK; t += 256) {
    Routing r = routing[t];
    myc += ((s == 0 ? r.i0 : r.i1) == e);
  }
  ps[tid] = myc;
  __syncthreads();
  for (int off = 1; off < 256; off <<= 1) {     // inclusive log-step scan
    int v = (tid >= off) ? ps[tid - off] : 0;
    __syncthreads();
    ps[tid] += v;
    __syncthreads();
  }
  int base = cur[blockIdx.x] + ps[tid] - myc;   // exclusive prefix + slot base
  for (int t = tid; t < NTOK; t += 256) {
    Routing r = routing[t];
    int ei = (s == 0 ? r.i0 : r.i1);
    if (ei == e) {
      list[s * NTOK + base] = t;
      wl[s * NTOK + base] = (s == 0 ? r.w0 : r.w1);
      ++base;
    }
  }
}

// ---------------- fused expert: (x@W1)*silu(x@Wg) @ W2, scaled ----------------
// 64 tokens x 1 head per block; 4 waves each own 16 tokens, out[16][128] in regs.
// Register-double-buffered weight pipeline: 36 uniform groups (8 loads + 8 MFMA);
// group g+1's loads issue before group g's MFMAs -> L2 latency hides under compute.
// Fully unrolled so all bw[] indices are compile-time (no scratch).
__global__ __launch_bounds__(256, 3) void expert_kernel(
    const float* __restrict__ x,
    const unsigned short* __restrict__ w1P,
    const unsigned short* __restrict__ wgP,
    const unsigned short* __restrict__ w2P,
    const int* __restrict__ list, const float* __restrict__ wl,
    const int4* __restrict__ table,
    float* __restrict__ out, const int slot)
{
  extern __shared__ char smem[];
  char* xs = smem;            // 64 rows * 256B bf16, XOR-swizzled by (row&7)<<4
  char* Pb = smem + 16384;    // 4 waves * 1536B: P scratch, 16 rows * 80B (pad)
  const int4 tb = table[slot * ENTRIES + blockIdx.x];
  const int e = tb.x, rbeg = tb.y, rcnt = tb.z, n = tb.w;
  if (rcnt == 0) return;
  const int* lst = list + slot * NTOK + rbeg;
  const float* wls = wl + slot * NTOK + rbeg;
  const int tid = threadIdx.x;

  // ---- gather x rows: fp32 global -> bf16 swizzled LDS ----
  {
    const int cpos = tid & 31;      // float4 index within a 128-float row
    const int rsub = tid >> 5;      // 0..7
    #pragma unroll
    for (int it = 0; it < 8; ++it) {
      int row = it * 8 + rsub;
      unsigned int lo = 0, hi = 0;
      if (row < rcnt) {
        int tok = lst[row];
        float4 v = reinterpret_cast<const float4*>(x + ((size_t)tok * NHEAD + n) * DDIM)[cpos];
        lo = (unsigned)f2bf(v.x) | ((unsigned)f2bf(v.y) << 16);
        hi = (unsigned)f2bf(v.z) | ((unsigned)f2bf(v.w) << 16);
      }
      int byte = row * 256 + ((cpos * 8) ^ ((row & 7) << 4));
      *reinterpret_cast<uint2*>(xs + byte) = make_uint2(lo, hi);
    }
  }
  __syncthreads();               // the ONLY block-wide barrier

  const int wid = tid >> 6, lane = tid & 63;
  const int lr = lane & 15, lq = lane >> 4;
  char* pw = Pb + wid * 1536;    // wave-private transpose scratch
  const f32x4 z4 = {0.f, 0.f, 0.f, 0.f};

  // x A-frags for this wave's 16 tokens (rows wid*16 .. wid*16+15)
  short8 a[4];
  #pragma unroll
  for (int kk = 0; kk < 4; ++kk) {
    int row = wid * 16 + lr;
    int byte = row * 256 + (((kk * 32 + lq * 8) * 2) ^ ((row & 7) << 4));
    a[kk] = *reinterpret_cast<const short8*>(xs + byte);
  }

  f32x4 acc[8];                  // out[16 tok][128 d] = 8 col-tiles
  #pragma unroll
  for (int ct = 0; ct < 8; ++ct) acc[ct] = z4;

  const unsigned short* w1b = w1P + (size_t)(e * NHEAD + n) * (4 * 24 * 512);
  const unsigned short* wgb = wgP + (size_t)(e * NHEAD + n) * (4 * 24 * 512);
  const unsigned short* w2b = w2P + (size_t)(e * NHEAD + n) * (12 * 8 * 512);

  short8 bw[2][8];               // double-buffered weight group (64 VGPR)

  // prologue: load group 0 = (chunk 0, stage-1 ctg=0) into bw[0]
  #pragma unroll
  for (int kk = 0; kk < 4; ++kk) {
    bw[0][kk]     = *reinterpret_cast<const short8*>(w1b + ((size_t)(kk * 24 + 0) * 64 + lane) * 8);
    bw[0][kk + 4] = *reinterpret_cast<const short8*>(wgb + ((size_t)(kk * 24 + 0) * 64 + lane) * 8);
  }

  #pragma unroll
  for (int c = 0; c < 12; ++c) {       // 12 chunks of 32 h-values, 3 groups each
    const int p0 = c & 1;              // parity of groups 3c and 3c+2
    const int p1 = p0 ^ 1;             // parity of group 3c+1

    // ---- group 3c: stage-1 ctg=2c (uses bw[p0]); prefetch group 3c+1 ----
    #pragma unroll
    for (int kk = 0; kk < 4; ++kk) {
      bw[p1][kk]     = *reinterpret_cast<const short8*>(w1b + ((size_t)(kk * 24 + 2 * c + 1) * 64 + lane) * 8);
      bw[p1][kk + 4] = *reinterpret_cast<const short8*>(wgb + ((size_t)(kk * 24 + 2 * c + 1) * 64 + lane) * 8);
    }
    {
      f32x4 ah = z4, ag = z4;
      #pragma unroll
      for (int kk = 0; kk < 4; ++kk) {
        ah = __builtin_amdgcn_mfma_f32_16x16x32_bf16(a[kk], bw[p0][kk],     ah, 0, 0, 0);
        ag = __builtin_amdgcn_mfma_f32_16x16x32_bf16(a[kk], bw[p0][kk + 4], ag, 0, 0, 0);
      }
      #pragma unroll
      for (int r = 0; r < 4; ++r) {
        float h1 = ah[r], g = ag[r];
        float val = h1 * g * __builtin_amdgcn_rcpf(1.f + __expf(-g));  // silu
        *reinterpret_cast<unsigned short*>(pw + (lq * 4 + r) * 80 + lr * 2) = f2bf(val);
      }
    }

    // ---- group 3c+1: stage-1 ctg=2c+1 (uses bw[p1]); prefetch stage-2 ----
    #pragma unroll
    for (int ct = 0; ct < 8; ++ct)
      bw[p0][ct] = *reinterpret_cast<const short8*>(w2b + ((size_t)(c * 8 + ct) * 64 + lane) * 8);
    {
      f32x4 ah = z4, ag = z4;
      #pragma unroll
      for (int kk = 0; kk < 4; ++kk) {
        ah = __builtin_amdgcn_mfma_f32_16x16x32_bf16(a[kk], bw[p1][kk],     ah, 0, 0, 0);
        ag = __builtin_amdgcn_mfma_f32_16x16x32_bf16(a[kk], bw[p1][kk + 4], ag, 0, 0, 0);
      }
      #pragma unroll
      for (int r = 0; r < 4; ++r) {
        float h1 = ah[r], g = ag[r];
        float val = h1 * g * __builtin_amdgcn_rcpf(1.f + __expf(-g));  // silu
        *reinterpret_cast<unsigned short*>(pw + (lq * 4 + r) * 80 + (16 + lr) * 2) = f2bf(val);
      }
    }

    // ---- group 3c+2: stage-2 (uses bw[p0]); prefetch next chunk's stage-1 ----
    if (c < 11) {
      #pragma unroll
      for (int kk = 0; kk < 4; ++kk) {
        bw[p1][kk]     = *reinterpret_cast<const short8*>(w1b + ((size_t)(kk * 24 + 2 * c + 2) * 64 + lane) * 8);
        bw[p1][kk + 4] = *reinterpret_cast<const short8*>(wgb + ((size_t)(kk * 24 + 2 * c + 2) * 64 + lane) * 8);
      }
    }
    {
      short8 a2 = *reinterpret_cast<const short8*>(pw + lr * 80 + lq * 16);
      #pragma unroll
      for (int ct = 0; ct < 8; ++ct)
        acc[ct] = __builtin_amdgcn_mfma_f32_16x16x32_bf16(a2, bw[p0][ct], acc[ct], 0, 0, 0);
    }
  }

  // ---- epilogue: scale by routing weight, store/accumulate ----
  #pragma unroll
  for (int r = 0; r < 4; ++r) {
    int lrow = wid * 16 + lq * 4 + r;
    if (lrow < rcnt) {
      int tok = lst[lrow];
      float wt = wls[lrow];
      float* op = out + ((size_t)tok * NHEAD + n) * DDIM;
      #pragma unroll
      for (int ct = 0; ct < 8; ++ct) {
        int col = ct * 16 + lr;
        float v = acc[ct][r] * wt;
        if (slot == 0) op[col] = v;   // pass 0: every token exactly once
        else          op[col] += v;   // pass 1: unique writer, after pass 0
      }
    }
  }
}

extern "C" void kernel_launch(void* const* d_in, const int* in_sizes, int n_in,
                              void* d_out, int out_size, void* d_ws, size_t ws_size,
                              hipStream_t stream) {
  const float* x  = (const float*)d_in[0];
  const float* rw = (const float*)d_in[1];
  const float* w1 = (const float*)d_in[2];
  const float* wg = (const float*)d_in[3];
  const float* w2 = (const float*)d_in[4];
  float* out = (float*)d_out;
  char* ws = (char*)d_ws;

  unsigned short* w1P = (unsigned short*)(ws + OFF_W1P);
  unsigned short* wgP = (unsigned short*)(ws + OFF_WGP);
  unsigned short* w2P = (unsigned short*)(ws + OFF_W2P);
  Routing* routing = (Routing*)(ws + OFF_ROUT);
  int* cnt = (int*)(ws + OFF_CNT);
  int* cur = cnt + 16;
  int4* table = (int4*)(ws + OFF_TAB);
  int* list = (int*)(ws + OFF_LIST);
  float* wl = (float*)(ws + OFF_WL);

  convA_kernel<<<dim3(4, 128, 2), 256, 0, stream>>>(w1, wg, w1P, wgP);
  convB_kernel<<<dim3(12, 128, 1), 256, 0, stream>>>(w2, w2P);
  router_kernel<<<512, 256, 0, stream>>>(x, rw, routing);
  count_kernel<<<16, 256, 0, stream>>>(routing, cnt);
  build_kernel<<<1, 256, 0, stream>>>(cnt, cur, table);
  compact_kernel<<<16, 256, 0, stream>>>(routing, cur, list, wl);
  expert_kernel<<<ENTRIES, 256, 22528, stream>>>(
      x, w1P, wgP, w2P, list, wl, table, out, 0);
  expert_kernel<<<ENTRIES, 256, 22528, stream>>>(
      x, w1P, wgP, w2P, list, wl, table, out, 1);
}